// Round 9
// baseline (325.241 us; speedup 1.0000x reference)
//
#include <hip/hip_runtime.h>
#include <math.h>

#define NQ 12
#define DIM 4096
#define NGATES 36
#define NROUND 9

typedef float f32x4 __attribute__((ext_vector_type(4)));
typedef __fp16 fp16x2 __attribute__((ext_vector_type(2)));
typedef __fp16 fp16x4 __attribute__((ext_vector_type(4)));
typedef __fp16 fp16x8 __attribute__((ext_vector_type(8)));

// GF(2)-linear LDS swizzle (bijective on 12 bits): sw(a^b) = sw(a)^sw(b)
constexpr unsigned swz(unsigned x) { return x ^ (x >> 4); }

// ---- compile-time circuit plan: CNOTs folded into GF(2) index maps ----
// Gate on logical bit b: pair mask m = M*e_b, "1"-selector = row b of M^-1.
// 4 gates per round; round = dense 16x16 complex matrix on the 4-bit slot
// subspace, applied to 256 cosets via MFMA (K=32 re/im-interleaved).
struct Round {
  unsigned s[4];       // selectors of the 4 gates
  unsigned l[4];       // sorted pivot low-masks for 4-zero-bit insertion
  unsigned cbsw8[16];  // swizzled byte offsets of the 16 coset slots
  unsigned dt[4];      // base8 XOR-delta for coset c ^= tt*16 (tile step)
};
struct PlanT {
  Round rd[NROUND];
  unsigned zsel[NQ];
};

constexpr PlanT make_plan() {
  PlanT P{};
  unsigned Mcol[NQ] = {}, Minv[NQ] = {};
  for (int i = 0; i < NQ; ++i) { Mcol[i] = 1u << i; Minv[i] = 1u << i; }
  unsigned gm[NGATES] = {}, gs[NGATES] = {};
  int g = 0;
  for (int L = 0; L < 3; ++L) {
    for (int q = 0; q < NQ; ++q) { int b = NQ - 1 - q; gm[g] = Mcol[b]; gs[g] = Minv[b]; ++g; }
    for (int q = 0; q < NQ; ++q) {
      int bc = NQ - 1 - q, bt = NQ - 1 - ((q + 1) % NQ);
      Mcol[bc] ^= Mcol[bt];
      Minv[bt] ^= Minv[bc];
    }
  }
  for (int r = 0; r < NROUND; ++r) {
    unsigned m[4], red[4];
    for (int k = 0; k < 4; ++k) { m[k] = gm[4*r+k]; red[k] = m[k]; P.rd[r].s[k] = gs[4*r+k]; }
    for (int a = 0; a < 4; ++a) {
      unsigned p = red[a] & (0u - red[a]);
      for (int b = a + 1; b < 4; ++b) if (red[b] & p) red[b] ^= red[a];
    }
    unsigned piv[4];
    for (int a = 0; a < 4; ++a) piv[a] = red[a] & (0u - red[a]);
    for (int a = 0; a < 4; ++a)
      for (int b = a + 1; b < 4; ++b)
        if (piv[a] > piv[b]) { unsigned tp = piv[a]; piv[a] = piv[b]; piv[b] = tp; }
    for (int a = 0; a < 4; ++a) P.rd[r].l[a] = piv[a] - 1u;
    for (int d = 0; d < 16; ++d) {
      unsigned c = 0;
      for (int k = 0; k < 4; ++k) if (d & (1 << k)) c ^= m[k];
      P.rd[r].cbsw8[d] = swz(c) << 3;
    }
    // tile deltas: full base8-linear image of coset step tt*16
    for (int tt = 0; tt < 4; ++tt) {
      unsigned c = (unsigned)tt << 4;
      unsigned j = c;
      j = ((j & ~P.rd[r].l[0]) << 1) | (j & P.rd[r].l[0]);
      j = ((j & ~P.rd[r].l[1]) << 1) | (j & P.rd[r].l[1]);
      j = ((j & ~P.rd[r].l[2]) << 1) | (j & P.rd[r].l[2]);
      j = ((j & ~P.rd[r].l[3]) << 1) | (j & P.rd[r].l[3]);
      unsigned d = swz(j) << 3;
      for (int k = 0; k < 4; ++k)
        if (__builtin_popcount(j & P.rd[r].s[k]) & 1) d ^= P.rd[r].cbsw8[1u << k];
      P.rd[r].dt[tt] = d;
    }
  }
  for (int q = 0; q < NQ; ++q) P.zsel[q] = Minv[NQ - 1 - q];
  return P;
}

constexpr PlanT PLAN = make_plan();

// ---- prep: per round build the dense 16x16 complex tensor-product matrix,
// emit 4 fp16 A-operand matrices [16 rows s][32 k] row-major (hi/lo split).
__global__ void qc_prep(const float* __restrict__ params, __fp16* __restrict__ amat) {
  int t = threadIdx.x;             // 256 threads; 144 used
  int r = t >> 4, s = t & 15;
  if (r >= NROUND) return;
  float U[4][8];
  for (int k = 0; k < 4; ++k) {
    int gg = r * 4 + k;
    float h1 = params[3*gg+0]*0.5f, hh2 = params[3*gg+1]*0.5f, h3 = params[3*gg+2]*0.5f;
    float c1 = cosf(h1), s1 = sinf(h1);
    float c2 = cosf(hh2), s2 = sinf(hh2);
    float c3 = cosf(h3), s3 = sinf(h3);
    float a00r =  c2*c1, a00i =  s2*s1;
    float a01r = -s2*c1, a01i = -c2*s1;
    float a10r =  s2*c1, a10i = -c2*s1;
    float a11r =  c2*c1, a11i = -s2*s1;
    U[k][0] = c3*a00r + s3*a00i;  U[k][1] = c3*a00i - s3*a00r;
    U[k][2] = c3*a01r + s3*a01i;  U[k][3] = c3*a01i - s3*a01r;
    U[k][4] = c3*a10r - s3*a10i;  U[k][5] = c3*a10i + s3*a10r;
    U[k][6] = c3*a11r - s3*a11i;  U[k][7] = c3*a11i + s3*a11r;
  }
  __fp16* b0 = amat + r*2048 + s*32;   // Are_hi row
  __fp16* b1 = b0 + 512;               // Are_lo
  __fp16* b2 = b0 + 1024;              // Aim_hi
  __fp16* b3 = b0 + 1536;              // Aim_lo
  for (int j = 0; j < 16; ++j) {
    float pr = 1.f, pi = 0.f;
    for (int k = 0; k < 4; ++k) {
      int idx = ((((s >> k) & 1) * 2) + ((j >> k) & 1)) * 2;
      float gr = U[k][idx], gi = U[k][idx + 1];
      float npr = pr * gr - pi * gi;
      pi = pr * gi + pi * gr;
      pr = npr;
    }
    float v0_ =  pr; __fp16 e0 = (__fp16)v0_;
    float v1_ = -pi; __fp16 e1 = (__fp16)v1_;
    float v2_ =  pi; __fp16 e2 = (__fp16)v2_;
    float v3_ =  pr; __fp16 e3 = (__fp16)v3_;
    b0[2*j]   = e0;  b1[2*j]   = (__fp16)(v0_ - (float)e0);
    b0[2*j+1] = e1;  b1[2*j+1] = (__fp16)(v1_ - (float)e1);
    b2[2*j]   = e2;  b3[2*j]   = (__fp16)(v2_ - (float)e2);
    b2[2*j+1] = e3;  b3[2*j+1] = (__fp16)(v3_ - (float)e3);
  }
}

// pack 4 float2 -> fp16 hi + lo fragments
__device__ __forceinline__ void mk_b(const float2* A, fp16x8& hi, fp16x8& lo) {
  fp16x2 p0 = __builtin_amdgcn_cvt_pkrtz(A[0].x, A[0].y);
  fp16x2 p1 = __builtin_amdgcn_cvt_pkrtz(A[1].x, A[1].y);
  fp16x2 p2 = __builtin_amdgcn_cvt_pkrtz(A[2].x, A[2].y);
  fp16x2 p3 = __builtin_amdgcn_cvt_pkrtz(A[3].x, A[3].y);
  fp16x2 q0 = __builtin_amdgcn_cvt_pkrtz(A[0].x - (float)p0[0], A[0].y - (float)p0[1]);
  fp16x2 q1 = __builtin_amdgcn_cvt_pkrtz(A[1].x - (float)p1[0], A[1].y - (float)p1[1]);
  fp16x2 q2 = __builtin_amdgcn_cvt_pkrtz(A[2].x - (float)p2[0], A[2].y - (float)p2[1]);
  fp16x2 q3 = __builtin_amdgcn_cvt_pkrtz(A[3].x - (float)p3[0], A[3].y - (float)p3[1]);
  fp16x4 u01 = __builtin_shufflevector(p0, p1, 0, 1, 2, 3);
  fp16x4 u23 = __builtin_shufflevector(p2, p3, 0, 1, 2, 3);
  hi = __builtin_shufflevector(u01, u23, 0, 1, 2, 3, 4, 5, 6, 7);
  fp16x4 w01 = __builtin_shufflevector(q0, q1, 0, 1, 2, 3);
  fp16x4 w23 = __builtin_shufflevector(q2, q3, 0, 1, 2, 3);
  lo = __builtin_shufflevector(w01, w23, 0, 1, 2, 3, 4, 5, 6, 7);
}

__global__ __launch_bounds__(256)
__attribute__((amdgpu_waves_per_eu(2)))
void qc_main(const float* __restrict__ x, const __fp16* __restrict__ amat,
             float* __restrict__ out) {
  __shared__ float2 sst[2 * DIM];    // 65536 B -> 2 blocks/CU; 2 rows/block
  char* sb = (char*)sst;
  const int t = threadIdx.x;
  const long rp = blockIdx.x;        // row-pair index

  // ---- stage both rows (im=0), accumulate sums of squares ----
  const float4* x40 = (const float4*)(x + (size_t)(2 * rp) * DIM);
  const float4* x41 = (const float4*)(x + (size_t)(2 * rp + 1) * DIM);
  float ssq0 = 0.f, ssq1 = 0.f;
#pragma unroll
  for (int k = 0; k < 4; ++k) {
    float4 a = x40[t + 256*k];
    float4 b = x41[t + 256*k];
    int j0 = 4*(t + 256*k);
    unsigned o0 = swz((unsigned)j0)     << 3;
    unsigned o1 = swz((unsigned)(j0+1)) << 3;
    unsigned o2 = swz((unsigned)(j0+2)) << 3;
    unsigned o3 = swz((unsigned)(j0+3)) << 3;
    *(float2*)(sb + o0) = make_float2(a.x, 0.f);
    *(float2*)(sb + o1) = make_float2(a.y, 0.f);
    *(float2*)(sb + o2) = make_float2(a.z, 0.f);
    *(float2*)(sb + o3) = make_float2(a.w, 0.f);
    *(float2*)(sb + (o0 | 0x8000u)) = make_float2(b.x, 0.f);
    *(float2*)(sb + (o1 | 0x8000u)) = make_float2(b.y, 0.f);
    *(float2*)(sb + (o2 | 0x8000u)) = make_float2(b.z, 0.f);
    *(float2*)(sb + (o3 | 0x8000u)) = make_float2(b.w, 0.f);
    ssq0 += a.x*a.x + a.y*a.y + a.z*a.z + a.w*a.w;
    ssq1 += b.x*b.x + b.y*b.y + b.z*b.z + b.w*b.w;
  }
#pragma unroll
  for (int off = 32; off > 0; off >>= 1) {
    ssq0 += __shfl_down(ssq0, off, 64);
    ssq1 += __shfl_down(ssq1, off, 64);
  }
  __syncthreads();

  // ---- 9 rounds; dense 16x16 complex gate-product via MFMA, 2 rows.
  // Addressing + A-fragments computed ONCE per round, shared by both rows.
  // Per-lane read-set == write-set (C/D row = q*4+reg matches B k-frag).
#pragma unroll 1
  for (int r = 0; r < NROUND; ++r) {
    const unsigned s0 = PLAN.rd[r].s[0], sA = PLAN.rd[r].s[1];
    const unsigned sB = PLAN.rd[r].s[2], sC = PLAN.rd[r].s[3];
    const unsigned l0 = PLAN.rd[r].l[0], l1 = PLAN.rd[r].l[1];
    const unsigned l2 = PLAN.rd[r].l[2], l3 = PLAN.rd[r].l[3];
    const unsigned CB1 = PLAN.rd[r].cbsw8[1], CB2 = PLAN.rd[r].cbsw8[2];
    const unsigned CB3 = PLAN.rd[r].cbsw8[3];
    const unsigned C4 = PLAN.rd[r].cbsw8[4], C8 = PLAN.rd[r].cbsw8[8];
    const unsigned dts[4] = {0u, PLAN.rd[r].dt[1], PLAN.rd[r].dt[2], PLAN.rd[r].dt[3]};

    // coset for tile 0: c0 = wave*64 + (lane&15)
    unsigned j = ((unsigned)t & 0xC0u) | ((unsigned)t & 15u);
    j = ((j & ~l0) << 1) | (j & l0);
    j = ((j & ~l1) << 1) | (j & l1);
    j = ((j & ~l2) << 1) | (j & l2);
    j = ((j & ~l3) << 1) | (j & l3);
    unsigned adj8 = 0;
    adj8 ^= (unsigned)(-(int)(__popc(j & s0) & 1)) & CB1;
    adj8 ^= (unsigned)(-(int)(__popc(j & sA) & 1)) & CB2;
    adj8 ^= (unsigned)(-(int)(__popc(j & sB) & 1)) & C4;
    adj8 ^= (unsigned)(-(int)(__popc(j & sC) & 1)) & C8;
    const unsigned q = ((unsigned)t >> 4) & 3u;
    const unsigned qsel = ((q & 1u) ? C4 : 0u) ^ ((q & 2u) ? C8 : 0u);
    const unsigned b0a = (((j ^ (j >> 4)) << 3) ^ adj8) ^ qsel;

    // A-operand fragments, shared by both rows (L1-resident)
    const fp16x8* am = (const fp16x8*)(amat + (size_t)r * 2048);
    const int fo = (t & 15) * 4 + (int)q;
    const fp16x8 Arh = am[fo];
    const fp16x8 Arl = am[64 + fo];
    const fp16x8 Aih = am[128 + fo];
    const fp16x8 Ail = am[192 + fo];

#pragma unroll
    for (int tt = 0; tt < 4; ++tt) {
      const unsigned bb = b0a ^ dts[tt];
      const unsigned a0 = bb, a1 = bb ^ CB1, a2 = bb ^ CB2, a3 = bb ^ CB3;
      // row 0 + row 1 reads (independent chains)
      float2 A0[4], A1[4];
      A0[0] = *(const float2*)(sb + a0);
      A0[1] = *(const float2*)(sb + a1);
      A0[2] = *(const float2*)(sb + a2);
      A0[3] = *(const float2*)(sb + a3);
      A1[0] = *(const float2*)(sb + (a0 | 0x8000u));
      A1[1] = *(const float2*)(sb + (a1 | 0x8000u));
      A1[2] = *(const float2*)(sb + (a2 | 0x8000u));
      A1[3] = *(const float2*)(sb + (a3 | 0x8000u));
      fp16x8 Bh0, Bl0, Bh1, Bl1;
      mk_b(A0, Bh0, Bl0);
      mk_b(A1, Bh1, Bl1);

      // 6-term hi/lo product per row (lo x lo dropped), chains interleaved
      f32x4 re0 = {0.f,0.f,0.f,0.f}, im0 = {0.f,0.f,0.f,0.f};
      f32x4 re1 = {0.f,0.f,0.f,0.f}, im1 = {0.f,0.f,0.f,0.f};
      re0 = __builtin_amdgcn_mfma_f32_16x16x32_f16(Arh, Bh0, re0, 0, 0, 0);
      re1 = __builtin_amdgcn_mfma_f32_16x16x32_f16(Arh, Bh1, re1, 0, 0, 0);
      im0 = __builtin_amdgcn_mfma_f32_16x16x32_f16(Aih, Bh0, im0, 0, 0, 0);
      im1 = __builtin_amdgcn_mfma_f32_16x16x32_f16(Aih, Bh1, im1, 0, 0, 0);
      re0 = __builtin_amdgcn_mfma_f32_16x16x32_f16(Arl, Bh0, re0, 0, 0, 0);
      re1 = __builtin_amdgcn_mfma_f32_16x16x32_f16(Arl, Bh1, re1, 0, 0, 0);
      im0 = __builtin_amdgcn_mfma_f32_16x16x32_f16(Ail, Bh0, im0, 0, 0, 0);
      im1 = __builtin_amdgcn_mfma_f32_16x16x32_f16(Ail, Bh1, im1, 0, 0, 0);
      re0 = __builtin_amdgcn_mfma_f32_16x16x32_f16(Arh, Bl0, re0, 0, 0, 0);
      re1 = __builtin_amdgcn_mfma_f32_16x16x32_f16(Arh, Bl1, re1, 0, 0, 0);
      im0 = __builtin_amdgcn_mfma_f32_16x16x32_f16(Aih, Bl0, im0, 0, 0, 0);
      im1 = __builtin_amdgcn_mfma_f32_16x16x32_f16(Aih, Bl1, im1, 0, 0, 0);

      // writes (C/D: col = lane&15, row = q*4+reg -> same addrs)
      *(float2*)(sb + a0) = make_float2(re0[0], im0[0]);
      *(float2*)(sb + a1) = make_float2(re0[1], im0[1]);
      *(float2*)(sb + a2) = make_float2(re0[2], im0[2]);
      *(float2*)(sb + a3) = make_float2(re0[3], im0[3]);
      *(float2*)(sb + (a0 | 0x8000u)) = make_float2(re1[0], im1[0]);
      *(float2*)(sb + (a1 | 0x8000u)) = make_float2(re1[1], im1[1]);
      *(float2*)(sb + (a2 | 0x8000u)) = make_float2(re1[2], im1[2]);
      *(float2*)(sb + (a3 | 0x8000u)) = make_float2(re1[3], im1[3]);
    }
    __syncthreads();
  }

  // ---- measurement: 16 consecutive amps/thread per row, WHT low 4 bits ----
  const unsigned mbase8 = (((16u * (unsigned)t) ^ (unsigned)t) << 3);
  float zs[2][NQ];
#pragma unroll
  for (int rr = 0; rr < 2; ++rr) {
    const char* base = sb + (rr << 15);
    float p[16];
#pragma unroll
    for (int c = 0; c < 16; ++c) {
      float2 v = *(const float2*)(base + (mbase8 ^ ((unsigned)c << 3)));
      p[c] = v.x * v.x + v.y * v.y;
    }
#pragma unroll
    for (int b = 0; b < 4; ++b) {
#pragma unroll
      for (int c = 0; c < 16; ++c) {
        if (!(c & (1 << b))) {
          const int c1 = c | (1 << b);
          float u = p[c], v = p[c1];
          p[c] = u + v; p[c1] = u - v;
        }
      }
    }
#pragma unroll
    for (int qq = 0; qq < NQ; ++qq) {
      const unsigned m = PLAN.zsel[qq];
      const float v = p[m & 15u];
      const int sgn = __popc((unsigned)t & (m >> 4)) & 1;
      zs[rr][qq] = sgn ? -v : v;
    }
  }

  // ---- block reduction via LDS, both rows (separate halves) ----
  // per half: 6 float2 columns of 256 at k*2048; ssq at 12288; partials 12352.
  __syncthreads();               // all state reads done; safe to overwrite
#pragma unroll
  for (int rr = 0; rr < 2; ++rr) {
    char* base = sb + (rr << 15);
#pragma unroll
    for (int k = 0; k < 6; ++k)
      *(float2*)(base + (((unsigned)(k << 8) + (unsigned)t) << 3)) =
          make_float2(zs[rr][2*k], zs[rr][2*k+1]);
    if ((t & 63) == 0) *(float*)(base + 12288 + (t >> 6) * 4) = rr ? ssq1 : ssq0;
  }
  __syncthreads();
#pragma unroll
  for (int rr = 0; rr < 2; ++rr) {
    char* base = sb + (rr << 15);
    if (t < 192) {
      const int k = t >> 5, jj = t & 31;
      const char* cbp = base + (k << 11) + (jj << 3);
      float2 acc = *(const float2*)(cbp);
#pragma unroll
      for (int i = 1; i < 8; ++i) {       // stride 32 entries: conflict-free
        float2 vv = *(const float2*)(cbp + i * 256);
        acc.x += vv.x; acc.y += vv.y;
      }
#pragma unroll
      for (int off = 16; off > 0; off >>= 1) {
        acc.x += __shfl_down(acc.x, off, 32);
        acc.y += __shfl_down(acc.y, off, 32);
      }
      if (jj == 0) *(float2*)(base + 12352 + (k << 3)) = acc;
    }
  }
  __syncthreads();
  if (t < NQ) {
#pragma unroll
    for (int rr = 0; rr < 2; ++rr) {
      const char* base = sb + (rr << 15);
      const float* sq = (const float*)(base + 12288);
      const float den = sq[0] + sq[1] + sq[2] + sq[3];
      out[(2 * rp + rr) * NQ + t] = ((const float*)(base + 12352))[t] / den;
    }
  }
}

extern "C" void kernel_launch(void* const* d_in, const int* in_sizes, int n_in,
                              void* d_out, int out_size, void* d_ws, size_t ws_size,
                              hipStream_t stream) {
  const float* x = (const float*)d_in[0];
  const float* params = (const float*)d_in[1];
  float* out = (float*)d_out;
  __fp16* amat = (__fp16*)d_ws;                // 9 rounds * 4 mats * 16x32 fp16
  const int nrows = in_sizes[0] / DIM;         // 8192
  qc_prep<<<dim3(1), dim3(256), 0, stream>>>(params, amat);
  qc_main<<<dim3(nrows / 2), dim3(256), 0, stream>>>(x, amat, out);
}

// Round 10
// 305.034 us; speedup vs baseline: 1.0662x; 1.0662x over previous
//
#include <hip/hip_runtime.h>
#include <math.h>

#define NQ 12
#define DIM 4096
#define NGATES 36
#define NROUND 9

typedef float f32x4 __attribute__((ext_vector_type(4)));
typedef __fp16 fp16x2 __attribute__((ext_vector_type(2)));
typedef __fp16 fp16x4 __attribute__((ext_vector_type(4)));
typedef __fp16 fp16x8 __attribute__((ext_vector_type(8)));

// GF(2)-linear LDS swizzle (bijective on 12 bits): sw(a^b) = sw(a)^sw(b)
constexpr unsigned swz(unsigned x) { return x ^ (x >> 4); }
constexpr int pc(unsigned x) { int c = 0; while (x) { c += (int)(x & 1u); x >>= 1; } return c; }

// rank of the low-4-bit projections of n vectors over GF(2)
constexpr bool rank4(const unsigned* v, int n) {
  unsigned pivs[4] = {0, 0, 0, 0};
  int rk = 0;
  for (int i = 0; i < n; ++i) {
    unsigned x = v[i] & 15u;
    for (int bit = 3; bit >= 0; --bit) {
      if (!((x >> bit) & 1u)) continue;
      if (pivs[bit]) x ^= pivs[bit];
      else { pivs[bit] = x; ++rk; break; }
    }
  }
  return rk == 4;
}

// ---- compile-time circuit plan: CNOTs folded into GF(2) index maps ----
// Gate on logical bit b: pair mask m = M*e_b, "1"-selector = row b of M^-1.
// 4 gates per round; round = dense 16x16 complex matrix on the 4-bit slot
// subspace, applied to 256 cosets via MFMA (K=32 re/im-interleaved).
// NEW: per-round constexpr search over (gate partition, col-direction subset)
// so each wave-instruction's 64-lane address set has full rank in the
// bank-pair bits -> conflict-free b64 LDS access.
struct Round {
  unsigned s[4];       // selectors of the 4 gates (plan slot-bit order)
  unsigned gidx[4];    // slot bit k <- original gate index (for prep)
  unsigned colD[4];    // 12-bit col direction vectors (lane bits 0..3)
  unsigned waveD[2];   // wave direction vectors (lane bits 6..7)
  unsigned cbsw8[16];  // swizzled byte offsets of the 16 coset slots
  unsigned dt[4];      // base8 XOR-delta for the 4 tiles
};
struct PlanT {
  Round rd[NROUND];
  unsigned zsel[NQ];
};

constexpr PlanT make_plan() {
  PlanT P{};
  unsigned Mcol[NQ] = {}, Minv[NQ] = {};
  for (int i = 0; i < NQ; ++i) { Mcol[i] = 1u << i; Minv[i] = 1u << i; }
  unsigned gm[NGATES] = {}, gs[NGATES] = {};
  int g = 0;
  for (int L = 0; L < 3; ++L) {
    for (int q = 0; q < NQ; ++q) { int b = NQ - 1 - q; gm[g] = Mcol[b]; gs[g] = Minv[b]; ++g; }
    for (int q = 0; q < NQ; ++q) {
      int bc = NQ - 1 - q, bt = NQ - 1 - ((q + 1) % NQ);
      Mcol[bc] ^= Mcol[bt];
      Minv[bt] ^= Minv[bc];
    }
  }
  for (int r = 0; r < NROUND; ++r) {
    unsigned m0[4], sl0[4];
    for (int k = 0; k < 4; ++k) { m0[k] = gm[4*r+k]; sl0[k] = gs[4*r+k]; }
    // pivots of the span of the 4 masks
    unsigned red[4];
    for (int k = 0; k < 4; ++k) red[k] = m0[k];
    for (int a = 0; a < 4; ++a) {
      unsigned pp = red[a] & (0u - red[a]);
      for (int b = a + 1; b < 4; ++b) if (red[b] & pp) red[b] ^= red[a];
    }
    unsigned piv[4];
    for (int a = 0; a < 4; ++a) piv[a] = red[a] & (0u - red[a]);
    for (int a = 0; a < 4; ++a)
      for (int b = a + 1; b < 4; ++b)
        if (piv[a] > piv[b]) { unsigned tp = piv[a]; piv[a] = piv[b]; piv[b] = tp; }
    unsigned l[4];
    for (int a = 0; a < 4; ++a) l[a] = piv[a] - 1u;
    // complement basis: D[i] = insert(1<<i) (zeros at pivot positions)
    unsigned D[8];
    for (int i = 0; i < 8; ++i) {
      unsigned j = 1u << i;
      j = ((j & ~l[0]) << 1) | (j & l[0]);
      j = ((j & ~l[1]) << 1) | (j & l[1]);
      j = ((j & ~l[2]) << 1) | (j & l[2]);
      j = ((j & ~l[3]) << 1) | (j & l[3]);
      D[i] = j;
    }
    // search: gate partition x col-dir 4-subset for rank-4 bank-pair map
    const int gp[3][4] = {{0,1,2,3},{0,2,1,3},{0,3,1,2}};
    int bp = -1; unsigned bS = 0;
    for (int p = 0; p < 3 && bp < 0; ++p) {
      unsigned mm[4], ss[4];
      for (int k = 0; k < 4; ++k) { mm[k] = m0[gp[p][k]]; ss[k] = sl0[gp[p][k]]; }
      unsigned cbu[16];
      for (int d = 0; d < 16; ++d) {
        unsigned c = 0;
        for (int k = 0; k < 4; ++k) if ((d >> k) & 1) c ^= mm[k];
        cbu[d] = swz(c);
      }
      for (unsigned S = 0; S < 256 && bp < 0; ++S) {
        if (pc(S) != 4) continue;
        unsigned v[6]; int vi = 0;
        for (int i = 0; i < 8; ++i) if ((S >> i) & 1) {
          unsigned av = swz(D[i]);
          for (int k = 0; k < 4; ++k) if (pc(D[i] & ss[k]) & 1) av ^= cbu[1u << k];
          v[vi++] = av;
        }
        v[4] = cbu[4]; v[5] = cbu[8];
        if (rank4(v, 6)) { bp = p; bS = S; }
      }
    }
    if (bp < 0) { bp = 0; bS = 0x0Fu; }   // fallback: original assignment
    // commit: selectors / gate order / cb table
    unsigned mm[4];
    for (int k = 0; k < 4; ++k) {
      P.rd[r].gidx[k] = (unsigned)gp[bp][k];
      P.rd[r].s[k]    = sl0[gp[bp][k]];
      mm[k]           = m0[gp[bp][k]];
    }
    unsigned cbu[16];
    for (int d = 0; d < 16; ++d) {
      unsigned c = 0;
      for (int k = 0; k < 4; ++k) if ((d >> k) & 1) c ^= mm[k];
      cbu[d] = swz(c);
      P.rd[r].cbsw8[d] = cbu[d] << 3;
    }
    // direction assignment: chosen 4 -> col; remaining: 2 -> tiles, 2 -> waves
    unsigned cD[4], TD[2], WD[2];
    int nc = 0, other[4]; int no = 0;
    for (int i = 0; i < 8; ++i) {
      if ((bS >> i) & 1) cD[nc++] = D[i];
      else other[no++] = i;
    }
    TD[0] = D[other[0]]; TD[1] = D[other[1]];
    WD[0] = D[other[2]]; WD[1] = D[other[3]];
    for (int k = 0; k < 4; ++k) P.rd[r].colD[k] = cD[k];
    P.rd[r].waveD[0] = WD[0]; P.rd[r].waveD[1] = WD[1];
    // tile deltas: full addr-image of the tile direction combos
    for (int tt = 0; tt < 4; ++tt) {
      unsigned jt = ((tt & 1) ? TD[0] : 0u) ^ ((tt & 2) ? TD[1] : 0u);
      unsigned d8 = swz(jt);
      for (int k = 0; k < 4; ++k) if (pc(jt & P.rd[r].s[k]) & 1) d8 ^= cbu[1u << k];
      P.rd[r].dt[tt] = d8 << 3;
    }
  }
  for (int q = 0; q < NQ; ++q) P.zsel[q] = Minv[NQ - 1 - q];
  return P;
}

constexpr PlanT PLAN = make_plan();

// ---- prep: per round build the dense 16x16 complex tensor-product matrix,
// emit 4 fp16 A-operand matrices [16 rows s][32 k] row-major (hi/lo split).
// Slot bit k corresponds to gate PLAN.rd[r].gidx[k] (plan gate order).
__global__ void qc_prep(const float* __restrict__ params, __fp16* __restrict__ amat) {
  int t = threadIdx.x;             // 256 threads; 144 used
  int r = t >> 4, s = t & 15;
  if (r >= NROUND) return;
  float U[4][8];
  for (int k = 0; k < 4; ++k) {
    int gg = r * 4 + (int)PLAN.rd[r].gidx[k];
    float h1 = params[3*gg+0]*0.5f, hh2 = params[3*gg+1]*0.5f, h3 = params[3*gg+2]*0.5f;
    float c1 = cosf(h1), s1 = sinf(h1);
    float c2 = cosf(hh2), s2 = sinf(hh2);
    float c3 = cosf(h3), s3 = sinf(h3);
    float a00r =  c2*c1, a00i =  s2*s1;
    float a01r = -s2*c1, a01i = -c2*s1;
    float a10r =  s2*c1, a10i = -c2*s1;
    float a11r =  c2*c1, a11i = -s2*s1;
    U[k][0] = c3*a00r + s3*a00i;  U[k][1] = c3*a00i - s3*a00r;
    U[k][2] = c3*a01r + s3*a01i;  U[k][3] = c3*a01i - s3*a01r;
    U[k][4] = c3*a10r - s3*a10i;  U[k][5] = c3*a10i + s3*a10r;
    U[k][6] = c3*a11r - s3*a11i;  U[k][7] = c3*a11i + s3*a11r;
  }
  __fp16* b0 = amat + r*2048 + s*32;   // Are_hi row
  __fp16* b1 = b0 + 512;               // Are_lo
  __fp16* b2 = b0 + 1024;              // Aim_hi
  __fp16* b3 = b0 + 1536;              // Aim_lo
  for (int j = 0; j < 16; ++j) {
    float pr = 1.f, pi = 0.f;
    for (int k = 0; k < 4; ++k) {
      int idx = ((((s >> k) & 1) * 2) + ((j >> k) & 1)) * 2;
      float gr = U[k][idx], gi = U[k][idx + 1];
      float npr = pr * gr - pi * gi;
      pi = pr * gi + pi * gr;
      pr = npr;
    }
    float v0_ =  pr; __fp16 e0 = (__fp16)v0_;
    float v1_ = -pi; __fp16 e1 = (__fp16)v1_;
    float v2_ =  pi; __fp16 e2 = (__fp16)v2_;
    float v3_ =  pr; __fp16 e3 = (__fp16)v3_;
    b0[2*j]   = e0;  b1[2*j]   = (__fp16)(v0_ - (float)e0);
    b0[2*j+1] = e1;  b1[2*j+1] = (__fp16)(v1_ - (float)e1);
    b2[2*j]   = e2;  b3[2*j]   = (__fp16)(v2_ - (float)e2);
    b2[2*j+1] = e3;  b3[2*j+1] = (__fp16)(v3_ - (float)e3);
  }
}

__global__ __launch_bounds__(256)
__attribute__((amdgpu_waves_per_eu(4, 5)))
void qc_main(const float* __restrict__ x, const __fp16* __restrict__ amat,
             float* __restrict__ out) {
  __shared__ float2 sst[DIM];        // 32768 B
  char* sb = (char*)sst;
  const int t = threadIdx.x;
  const long row = blockIdx.x;

  // ---- stage x row (im=0), accumulate sum of squares ----
  const float4* x4 = (const float4*)(x + (size_t)row * DIM);
  float ssq = 0.f;
#pragma unroll
  for (int k = 0; k < 4; ++k) {
    float4 a = x4[t + 256*k];
    int j0 = 4*(t + 256*k);
    *(float2*)(sb + (swz((unsigned)j0)     << 3)) = make_float2(a.x, 0.f);
    *(float2*)(sb + (swz((unsigned)(j0+1)) << 3)) = make_float2(a.y, 0.f);
    *(float2*)(sb + (swz((unsigned)(j0+2)) << 3)) = make_float2(a.z, 0.f);
    *(float2*)(sb + (swz((unsigned)(j0+3)) << 3)) = make_float2(a.w, 0.f);
    ssq += a.x*a.x + a.y*a.y + a.z*a.z + a.w*a.w;
  }
#pragma unroll
  for (int off = 32; off > 0; off >>= 1) ssq += __shfl_down(ssq, off, 64);
  __syncthreads();

  // ---- 9 rounds; dense 16x16 complex gate-product via MFMA (R7 structure,
  // monolithic per-tile). j built from per-round conflict-free direction
  // vectors (constexpr rank-4 search in make_plan).
#pragma unroll 1
  for (int r = 0; r < NROUND; ++r) {
    const unsigned s0 = PLAN.rd[r].s[0], sA = PLAN.rd[r].s[1];
    const unsigned sB = PLAN.rd[r].s[2], sC = PLAN.rd[r].s[3];
    const unsigned cD0 = PLAN.rd[r].colD[0], cD1 = PLAN.rd[r].colD[1];
    const unsigned cD2 = PLAN.rd[r].colD[2], cD3 = PLAN.rd[r].colD[3];
    const unsigned W0 = PLAN.rd[r].waveD[0], W1 = PLAN.rd[r].waveD[1];
    const unsigned CB1 = PLAN.rd[r].cbsw8[1], CB2 = PLAN.rd[r].cbsw8[2];
    const unsigned CB3 = PLAN.rd[r].cbsw8[3];
    const unsigned C4 = PLAN.rd[r].cbsw8[4], C8 = PLAN.rd[r].cbsw8[8];
    const unsigned dts[4] = {0u, PLAN.rd[r].dt[1], PLAN.rd[r].dt[2], PLAN.rd[r].dt[3]};

    // coset rep for tile 0: XOR of chosen direction vectors
    unsigned j = 0;
    j ^= (unsigned)(-(int)((t >> 0) & 1)) & cD0;
    j ^= (unsigned)(-(int)((t >> 1) & 1)) & cD1;
    j ^= (unsigned)(-(int)((t >> 2) & 1)) & cD2;
    j ^= (unsigned)(-(int)((t >> 3) & 1)) & cD3;
    j ^= (unsigned)(-(int)((t >> 6) & 1)) & W0;
    j ^= (unsigned)(-(int)((t >> 7) & 1)) & W1;
    unsigned adj8 = 0;
    adj8 ^= (unsigned)(-(int)(__popc(j & s0) & 1)) & CB1;
    adj8 ^= (unsigned)(-(int)(__popc(j & sA) & 1)) & CB2;
    adj8 ^= (unsigned)(-(int)(__popc(j & sB) & 1)) & C4;
    adj8 ^= (unsigned)(-(int)(__popc(j & sC) & 1)) & C8;
    const unsigned q = ((unsigned)t >> 4) & 3u;
    const unsigned qsel = ((q & 1u) ? C4 : 0u) ^ ((q & 2u) ? C8 : 0u);
    const unsigned b0a = (((j ^ (j >> 4)) << 3) ^ adj8) ^ qsel;

    // A-operand fragments (uniform-ish global loads; L1/L2 resident)
    const fp16x8* am = (const fp16x8*)(amat + (size_t)r * 2048);
    const int fo = (t & 15) * 4 + (int)q;
    const fp16x8 Arh = am[fo];
    const fp16x8 Arl = am[64 + fo];
    const fp16x8 Aih = am[128 + fo];
    const fp16x8 Ail = am[192 + fo];

#pragma unroll
    for (int tt = 0; tt < 4; ++tt) {
      const unsigned bb = b0a ^ dts[tt];
      const unsigned a0 = bb, a1 = bb ^ CB1, a2 = bb ^ CB2, a3 = bb ^ CB3;
      const float2 A0 = *(const float2*)(sb + a0);
      const float2 A1 = *(const float2*)(sb + a1);
      const float2 A2 = *(const float2*)(sb + a2);
      const float2 A3 = *(const float2*)(sb + a3);
      // B fragment: k = q*8 + 2*jj + comp -> amp slot 4q+jj, re/im interleave
      fp16x2 p0 = __builtin_amdgcn_cvt_pkrtz(A0.x, A0.y);
      fp16x2 p1 = __builtin_amdgcn_cvt_pkrtz(A1.x, A1.y);
      fp16x2 p2 = __builtin_amdgcn_cvt_pkrtz(A2.x, A2.y);
      fp16x2 p3 = __builtin_amdgcn_cvt_pkrtz(A3.x, A3.y);
      fp16x2 q0 = __builtin_amdgcn_cvt_pkrtz(A0.x - (float)p0[0], A0.y - (float)p0[1]);
      fp16x2 q1 = __builtin_amdgcn_cvt_pkrtz(A1.x - (float)p1[0], A1.y - (float)p1[1]);
      fp16x2 q2 = __builtin_amdgcn_cvt_pkrtz(A2.x - (float)p2[0], A2.y - (float)p2[1]);
      fp16x2 q3 = __builtin_amdgcn_cvt_pkrtz(A3.x - (float)p3[0], A3.y - (float)p3[1]);
      fp16x4 u01 = __builtin_shufflevector(p0, p1, 0, 1, 2, 3);
      fp16x4 u23 = __builtin_shufflevector(p2, p3, 0, 1, 2, 3);
      fp16x8 Bhi = __builtin_shufflevector(u01, u23, 0, 1, 2, 3, 4, 5, 6, 7);
      fp16x4 w01 = __builtin_shufflevector(q0, q1, 0, 1, 2, 3);
      fp16x4 w23 = __builtin_shufflevector(q2, q3, 0, 1, 2, 3);
      fp16x8 Blo = __builtin_shufflevector(w01, w23, 0, 1, 2, 3, 4, 5, 6, 7);

      // 6-term hi/lo product (lo x lo dropped: ~2^-24 rel, negligible)
      f32x4 are = {0.f, 0.f, 0.f, 0.f}, aim = {0.f, 0.f, 0.f, 0.f};
      are = __builtin_amdgcn_mfma_f32_16x16x32_f16(Arh, Bhi, are, 0, 0, 0);
      are = __builtin_amdgcn_mfma_f32_16x16x32_f16(Arl, Bhi, are, 0, 0, 0);
      are = __builtin_amdgcn_mfma_f32_16x16x32_f16(Arh, Blo, are, 0, 0, 0);
      aim = __builtin_amdgcn_mfma_f32_16x16x32_f16(Aih, Bhi, aim, 0, 0, 0);
      aim = __builtin_amdgcn_mfma_f32_16x16x32_f16(Ail, Bhi, aim, 0, 0, 0);
      aim = __builtin_amdgcn_mfma_f32_16x16x32_f16(Aih, Blo, aim, 0, 0, 0);

      // C/D layout: col = lane&15 (coset), row = q*4+reg (slot) -> same addrs
      *(float2*)(sb + a0) = make_float2(are[0], aim[0]);
      *(float2*)(sb + a1) = make_float2(are[1], aim[1]);
      *(float2*)(sb + a2) = make_float2(are[2], aim[2]);
      *(float2*)(sb + a3) = make_float2(are[3], aim[3]);
    }
    __syncthreads();
  }

  // ---- measurement: 16 consecutive amps/thread, WHT over low 4 bits ----
  const unsigned mbase8 = (((16u * (unsigned)t) ^ (unsigned)t) << 3);
  float p[16];
#pragma unroll
  for (int c = 0; c < 16; ++c) {
    float2 v = *(const float2*)(sb + (mbase8 ^ ((unsigned)c << 3)));
    p[c] = v.x * v.x + v.y * v.y;
  }
#pragma unroll
  for (int b = 0; b < 4; ++b) {
#pragma unroll
    for (int c = 0; c < 16; ++c) {
      if (!(c & (1 << b))) {
        const int c1 = c | (1 << b);
        float u = p[c], v = p[c1];
        p[c] = u + v; p[c1] = u - v;
      }
    }
  }
  float zs[NQ];
#pragma unroll
  for (int qq = 0; qq < NQ; ++qq) {
    const unsigned m = PLAN.zsel[qq];
    const float v = p[m & 15u];
    const int sgn = __popc((unsigned)t & (m >> 4)) & 1;
    zs[qq] = sgn ? -v : v;
  }

  // ---- block reduction via LDS ----
  // layout: 6 float2 columns of 256 entries at k*2048; ssq at 12288;
  // partials at 12352.
  __syncthreads();               // all state reads done; safe to overwrite
#pragma unroll
  for (int k = 0; k < 6; ++k)
    *(float2*)(sb + (((unsigned)(k << 8) + (unsigned)t) << 3)) =
        make_float2(zs[2*k], zs[2*k+1]);
  if ((t & 63) == 0) *(float*)(sb + 12288 + (t >> 6) * 4) = ssq;
  __syncthreads();
  if (t < 192) {
    const int k = t >> 5, j = t & 31;
    const char* cbp = sb + (k << 11) + (j << 3);
    float2 acc = *(const float2*)(cbp);
#pragma unroll
    for (int i = 1; i < 8; ++i) {         // stride 32 entries: conflict-free
      float2 vv = *(const float2*)(cbp + i * 256);
      acc.x += vv.x; acc.y += vv.y;
    }
#pragma unroll
    for (int off = 16; off > 0; off >>= 1) {
      acc.x += __shfl_down(acc.x, off, 32);
      acc.y += __shfl_down(acc.y, off, 32);
    }
    if (j == 0) *(float2*)(sb + 12352 + (k << 3)) = acc;
  }
  __syncthreads();
  if (t < NQ) {
    const float* sq = (const float*)(sb + 12288);
    const float den = sq[0] + sq[1] + sq[2] + sq[3];
    out[row * NQ + t] = ((const float*)(sb + 12352))[t] / den;
  }
}

extern "C" void kernel_launch(void* const* d_in, const int* in_sizes, int n_in,
                              void* d_out, int out_size, void* d_ws, size_t ws_size,
                              hipStream_t stream) {
  const float* x = (const float*)d_in[0];
  const float* params = (const float*)d_in[1];
  float* out = (float*)d_out;
  __fp16* amat = (__fp16*)d_ws;                // 9 rounds * 4 mats * 16x32 fp16
  const int nrows = in_sizes[0] / DIM;         // 8192
  qc_prep<<<dim3(1), dim3(256), 0, stream>>>(params, amat);
  qc_main<<<dim3(nrows), dim3(256), 0, stream>>>(x, amat, out);
}